// Round 12
// baseline (400.854 us; speedup 1.0000x reference)
//
#include <hip/hip_runtime.h>
#include <hip/hip_fp16.h>

#define TPB 256
#define CAP 64     // bucket capacity per node
#define EPB 2048   // edges per part1 tile
#define BCAP 6144  // edge capacity per bin region
#define PREPB 784  // prep grid: multiple of 16, <= 1024 (4 blocks/CU @ 33KB LDS -> all resident)

typedef _Float16 half8 __attribute__((ext_vector_type(8)));
typedef _Float16 half2v __attribute__((ext_vector_type(2)));
typedef float floatx4 __attribute__((ext_vector_type(4)));

// ---------- W -> fp16 MFMA B-fragment order; zero binCnt + barrier state ----------
__global__ __launch_bounds__(TPB) void cvtw_k(const float* __restrict__ W, half8* __restrict__ W16,
                                              int* __restrict__ binCnt, int nzero) {
  int j = blockIdx.x * TPB + threadIdx.x;
  if (j < nzero) binCnt[j] = 0;  // bins + 16 leaf + 1 root
  if (j >= 3 * 2048) return;
  int layer = j >> 11;
  int r = j & 2047;
  int kf = r >> 7;
  int nn = r & 127;
  const float* Wl = W + (size_t)layer * 16384;
  half8 v;
#pragma unroll
  for (int jj = 0; jj < 8; jj++) v[jj] = (_Float16)Wl[(kf * 8 + jj) * 128 + nn];
  W16[j] = v;
}

// ---------- device-scope grid barrier (all blocks resident; 16-leaf tree) ----------
__device__ __forceinline__ void gbar(int* __restrict__ leaf, int* __restrict__ root,
                                     int perLeaf, int nroot) {
  __syncthreads();
  if (threadIdx.x == 0) {
    __threadfence();  // L2 writeback + visibility of this block's writes
    int li = blockIdx.x & 15;
    int lv = __hip_atomic_fetch_add(&leaf[li], 1, __ATOMIC_ACQ_REL, __HIP_MEMORY_SCOPE_AGENT);
    if (lv == perLeaf - 1)
      __hip_atomic_fetch_add(root, 1, __ATOMIC_ACQ_REL, __HIP_MEMORY_SCOPE_AGENT);
    while (__hip_atomic_load(root, __ATOMIC_ACQUIRE, __HIP_MEMORY_SCOPE_AGENT) < nroot)
      __builtin_amdgcn_s_sleep(8);
    __threadfence();  // invalidate local caches before reading others' data
  }
  __syncthreads();
}

// ---------- prep: [part1 tiles + gemm0 tiles] -> barrier -> [part2 bins] ----------
__global__ __launch_bounds__(TPB, 4) void prep_k(
    const float* __restrict__ x, const half8* __restrict__ W16,
    const int* __restrict__ src, const int* __restrict__ dst,
    int* __restrict__ binCnt, uint* __restrict__ binBuf,
    ushort* __restrict__ colidx, int* __restrict__ cnt, int* __restrict__ bar,
    _Float16* __restrict__ t, int E, int n, int nbins, int npart1, int ngemm) {
  __shared__ __align__(16) ushort lb[256 * CAP];  // 32 KB (part2); aliased as offs in part1
  __shared__ int lc[256];                         // hist (part1) / counters (part2)
  const int tid = threadIdx.x;
  int* offs = (int*)lb;

  // ===== phase A: part1 radix tiles + gemm0 tiles (independent) =====
  for (int u = blockIdx.x; u < npart1 + ngemm; u += PREPB) {
    if (u < npart1) {
      const int bb = u * EPB;
      lc[tid] = 0;
      __syncthreads();
      int sv[8], dv[8];
#pragma unroll
      for (int k = 0; k < 8; k++) {
        int i = bb + tid + k * TPB;
        if (i < E) { sv[k] = src[i]; dv[k] = dst[i]; }
        else { sv[k] = 0; dv[k] = -1; }
      }
#pragma unroll
      for (int k = 0; k < 8; k++)
        if (dv[k] >= 0) atomicAdd(&lc[dv[k] >> 8], 1);
      __syncthreads();
      if (tid < nbins) offs[tid] = lc[tid] ? atomicAdd(&binCnt[tid], lc[tid]) : 0;
      __syncthreads();
#pragma unroll
      for (int k = 0; k < 8; k++) {
        if (dv[k] >= 0) {
          int b = dv[k] >> 8;
          int r = atomicAdd(&offs[b], 1);
          if (r < BCAP)
            binBuf[(size_t)b * BCAP + r] = ((uint)(dv[k] & 255) << 16) | (uint)(ushort)sv[k];
        }
      }
      __syncthreads();
    } else {
      // gemm0 tile: t_raw = x @ W0 (no dis scale; agg0 applies it per edge)
      const int g = u - npart1;
      const int lane = tid & 63;
      const int wv = tid >> 6;
      const int m16 = lane & 15;
      const int q = lane >> 4;
      const int r0 = g * 64;
      half8 bfr[2][4];
#pragma unroll
      for (int nt2 = 0; nt2 < 2; nt2++) {
        const int ncol = 16 * (2 * wv + nt2) + m16;
#pragma unroll
        for (int kit = 0; kit < 4; kit++)
          bfr[nt2][kit] = W16[(kit * 4 + q) * 128 + ncol];
      }
      floatx4 acc[2][4];
#pragma unroll
      for (int a = 0; a < 2; a++)
#pragma unroll
        for (int b = 0; b < 4; b++) acc[a][b] = (floatx4){0.f, 0.f, 0.f, 0.f};
#pragma unroll
      for (int kit = 0; kit < 4; kit++) {
        half8 af[4];
#pragma unroll
        for (int rt = 0; rt < 4; rt++) {
          int row = r0 + 16 * rt + m16;
          half8 a = {0, 0, 0, 0, 0, 0, 0, 0};
          if (row < n) {
            const float4* hp = (const float4*)(x + (size_t)row * 128 + 32 * kit + 8 * q);
            float4 p0 = hp[0], p1 = hp[1];
            a = half8{(_Float16)p0.x, (_Float16)p0.y, (_Float16)p0.z, (_Float16)p0.w,
                      (_Float16)p1.x, (_Float16)p1.y, (_Float16)p1.z, (_Float16)p1.w};
          }
          af[rt] = a;
        }
#pragma unroll
        for (int rt = 0; rt < 4; rt++)
#pragma unroll
          for (int nt2 = 0; nt2 < 2; nt2++)
            acc[nt2][rt] = __builtin_amdgcn_mfma_f32_16x16x32_f16(af[rt], bfr[nt2][kit], acc[nt2][rt], 0, 0, 0);
      }
#pragma unroll
      for (int rt = 0; rt < 4; rt++) {
#pragma unroll
        for (int reg = 0; reg < 4; reg++) {
          int row = r0 + 16 * rt + 4 * q + reg;
          if (row < n) {
#pragma unroll
            for (int nt2 = 0; nt2 < 2; nt2++) {
              int col = 16 * (2 * wv + nt2) + m16;
              t[(size_t)row * 128 + col] = (_Float16)acc[nt2][rt][reg];
            }
          }
        }
      }
    }
  }

  // ===== grid barrier (all PREPB blocks resident) =====
  gbar(bar, bar + 16, PREPB / 16, 16);

  // ===== phase B: part2 — build buckets in LDS, dump coalesced =====
  for (int b = blockIdx.x; b < nbins; b += PREPB) {
    lc[tid] = 0;
    __syncthreads();
    int count = binCnt[b];
    if (count > BCAP) count = BCAP;
    for (int i = tid; i < count; i += TPB) {
      uint p = binBuf[(size_t)b * BCAP + i];
      int dl = (p >> 16) & 255;
      int s = p & 0xFFFF;
      int r = atomicAdd(&lc[dl], 1);
      if (r < CAP) lb[(dl << 6) + r] = (ushort)s;
    }
    __syncthreads();
    uint4* gb = (uint4*)(colidx + (size_t)b * 256 * CAP);
    const uint4* sb = (const uint4*)lb;
#pragma unroll
    for (int k = 0; k < 8; k++) gb[tid + TPB * k] = sb[tid + TPB * k];
    int node = b * 256 + tid;
    if (node < n) cnt[node] = lc[tid];
    __syncthreads();
  }
}

// ---------- t = rsqrt(cnt[row]+1) * (h @ W), fp16, layers 1-2 ----------
__global__ __launch_bounds__(TPB) void gemm_k(const _Float16* __restrict__ h, const half8* __restrict__ W16,
                                              const int* __restrict__ cnt, _Float16* __restrict__ t, int n) {
  const int tid = threadIdx.x;
  const int lane = tid & 63;
  const int wv = tid >> 6;
  const int m16 = lane & 15;
  const int q = lane >> 4;
  const int r0 = blockIdx.x * 64;
  half8 bfr[2][4];
#pragma unroll
  for (int nt2 = 0; nt2 < 2; nt2++) {
    const int ncol = 16 * (2 * wv + nt2) + m16;
#pragma unroll
    for (int kit = 0; kit < 4; kit++)
      bfr[nt2][kit] = W16[(kit * 4 + q) * 128 + ncol];
  }
  floatx4 acc[2][4];
#pragma unroll
  for (int a = 0; a < 2; a++)
#pragma unroll
    for (int b = 0; b < 4; b++) acc[a][b] = (floatx4){0.f, 0.f, 0.f, 0.f};
#pragma unroll
  for (int kit = 0; kit < 4; kit++) {
    half8 af[4];
#pragma unroll
    for (int rt = 0; rt < 4; rt++) {
      int row = r0 + 16 * rt + m16;
      half8 a = {0, 0, 0, 0, 0, 0, 0, 0};
      if (row < n) a = *(const half8*)(h + (size_t)row * 128 + 32 * kit + 8 * q);
      af[rt] = a;
    }
#pragma unroll
    for (int rt = 0; rt < 4; rt++)
#pragma unroll
      for (int nt2 = 0; nt2 < 2; nt2++)
        acc[nt2][rt] = __builtin_amdgcn_mfma_f32_16x16x32_f16(af[rt], bfr[nt2][kit], acc[nt2][rt], 0, 0, 0);
  }
#pragma unroll
  for (int rt = 0; rt < 4; rt++) {
#pragma unroll
    for (int reg = 0; reg < 4; reg++) {
      int row = r0 + 16 * rt + 4 * q + reg;
      if (row < n) {
        float dsc = rsqrtf((float)(cnt[row] + 1));
#pragma unroll
        for (int nt2 = 0; nt2 < 2; nt2++) {
          int col = 16 * (2 * wv + nt2) + m16;
          t[(size_t)row * 128 + col] = (_Float16)(acc[nt2][rt][reg] * dsc);
        }
      }
    }
  }
}

// ---------- aggregation (SCALE: layer-0 t is raw -> per-edge rsqrt; LAST: fused projection) ----------
#define GATH(k)  int s##k = __builtin_amdgcn_readlane(myIdx, k); uint v##k = t2u[(size_t)s##k * 64 + lane]; \
                 float w##k = SCALE ? rsqrtf((float)(cnt[s##k] + 1)) : 1.f;
#define CONS(k)  { float2 f_ = __half22float2(__builtin_bit_cast(__half2, v##k)); \
                   if (SCALE) { a0 = fmaf(f_.x, w##k, a0); a1 = fmaf(f_.y, w##k, a1); } \
                   else { a0 += f_.x; a1 += f_.y; } }

template <bool SCALE, bool LAST>
__global__ __launch_bounds__(TPB) void agg_k(const uint* __restrict__ t2u, const int* __restrict__ cnt,
                                             const ushort* __restrict__ colidx,
                                             const float* __restrict__ bias, _Float16* __restrict__ hout,
                                             const float* __restrict__ Wl, const float* __restrict__ bl,
                                             float* __restrict__ out, int n) {
  int wid = (blockIdx.x * TPB + threadIdx.x) >> 6;
  int lane = threadIdx.x & 63;
  if (wid >= n) return;
  int m = cnt[wid];
  float dd = rsqrtf((float)(m + 1));
  if (m > CAP) m = CAP;
  const size_t base = (size_t)wid * CAP;
  float a0 = 0.f, a1 = 0.f;
  if (m <= 32) {
    int myIdx = wid;  // pad slots -> self row (compensated below)
    if (lane < m) myIdx = (int)colidx[base + lane];
    if (m <= 16) {
      GATH(0) GATH(1) GATH(2) GATH(3) GATH(4) GATH(5) GATH(6) GATH(7)
      GATH(8) GATH(9) GATH(10) GATH(11) GATH(12) GATH(13) GATH(14) GATH(15)
      uint vw = t2u[(size_t)wid * 64 + lane];
      CONS(0) CONS(1) CONS(2) CONS(3) CONS(4) CONS(5) CONS(6) CONS(7)
      CONS(8) CONS(9) CONS(10) CONS(11) CONS(12) CONS(13) CONS(14) CONS(15)
      float2 fw = __half22float2(__builtin_bit_cast(__half2, vw));
      float sc = SCALE ? dd * (float)(m - 15) : (float)(m - 15);
      a0 = fmaf(fw.x, sc, a0); a1 = fmaf(fw.y, sc, a1);
    } else {
      GATH(0) GATH(1) GATH(2) GATH(3) GATH(4) GATH(5) GATH(6) GATH(7)
      GATH(8) GATH(9) GATH(10) GATH(11) GATH(12) GATH(13) GATH(14) GATH(15)
      GATH(16) GATH(17) GATH(18) GATH(19) GATH(20) GATH(21) GATH(22) GATH(23)
      GATH(24) GATH(25) GATH(26) GATH(27) GATH(28) GATH(29) GATH(30) GATH(31)
      uint vw = t2u[(size_t)wid * 64 + lane];
      CONS(0) CONS(1) CONS(2) CONS(3) CONS(4) CONS(5) CONS(6) CONS(7)
      CONS(8) CONS(9) CONS(10) CONS(11) CONS(12) CONS(13) CONS(14) CONS(15)
      CONS(16) CONS(17) CONS(18) CONS(19) CONS(20) CONS(21) CONS(22) CONS(23)
      CONS(24) CONS(25) CONS(26) CONS(27) CONS(28) CONS(29) CONS(30) CONS(31)
      float2 fw = __half22float2(__builtin_bit_cast(__half2, vw));
      float sc = SCALE ? dd * (float)(m - 31) : (float)(m - 31);
      a0 = fmaf(fw.x, sc, a0); a1 = fmaf(fw.y, sc, a1);
    }
  } else {  // 32 < m <= 64, rare
    int myIdx = 0;
    if (lane < m) myIdx = (int)colidx[base + lane];
    for (int e = 0; e < m; e += 8) {
      int s0 = __builtin_amdgcn_readlane(myIdx, e + 0);
      int s1 = __builtin_amdgcn_readlane(myIdx, e + 1);
      int s2 = __builtin_amdgcn_readlane(myIdx, e + 2);
      int s3 = __builtin_amdgcn_readlane(myIdx, e + 3);
      int s4 = __builtin_amdgcn_readlane(myIdx, e + 4);
      int s5 = __builtin_amdgcn_readlane(myIdx, e + 5);
      int s6 = __builtin_amdgcn_readlane(myIdx, e + 6);
      int s7 = __builtin_amdgcn_readlane(myIdx, e + 7);
      uint v0 = t2u[(size_t)s0 * 64 + lane];
      uint v1 = t2u[(size_t)s1 * 64 + lane];
      uint v2 = t2u[(size_t)s2 * 64 + lane];
      uint v3 = t2u[(size_t)s3 * 64 + lane];
      uint v4 = t2u[(size_t)s4 * 64 + lane];
      uint v5 = t2u[(size_t)s5 * 64 + lane];
      uint v6 = t2u[(size_t)s6 * 64 + lane];
      uint v7 = t2u[(size_t)s7 * 64 + lane];
      v1 = (e + 1 < m) ? v1 : 0u;
      v2 = (e + 2 < m) ? v2 : 0u;
      v3 = (e + 3 < m) ? v3 : 0u;
      v4 = (e + 4 < m) ? v4 : 0u;
      v5 = (e + 5 < m) ? v5 : 0u;
      v6 = (e + 6 < m) ? v6 : 0u;
      v7 = (e + 7 < m) ? v7 : 0u;
      float w0 = SCALE ? rsqrtf((float)(cnt[s0] + 1)) : 1.f;
      float w1 = SCALE ? rsqrtf((float)(cnt[s1] + 1)) : 1.f;
      float w2 = SCALE ? rsqrtf((float)(cnt[s2] + 1)) : 1.f;
      float w3 = SCALE ? rsqrtf((float)(cnt[s3] + 1)) : 1.f;
      float w4 = SCALE ? rsqrtf((float)(cnt[s4] + 1)) : 1.f;
      float w5 = SCALE ? rsqrtf((float)(cnt[s5] + 1)) : 1.f;
      float w6 = SCALE ? rsqrtf((float)(cnt[s6] + 1)) : 1.f;
      float w7 = SCALE ? rsqrtf((float)(cnt[s7] + 1)) : 1.f;
      float2 f;
      f = __half22float2(__builtin_bit_cast(__half2, v0)); a0 = fmaf(f.x, w0, a0); a1 = fmaf(f.y, w0, a1);
      f = __half22float2(__builtin_bit_cast(__half2, v1)); a0 = fmaf(f.x, w1, a0); a1 = fmaf(f.y, w1, a1);
      f = __half22float2(__builtin_bit_cast(__half2, v2)); a0 = fmaf(f.x, w2, a0); a1 = fmaf(f.y, w2, a1);
      f = __half22float2(__builtin_bit_cast(__half2, v3)); a0 = fmaf(f.x, w3, a0); a1 = fmaf(f.y, w3, a1);
      f = __half22float2(__builtin_bit_cast(__half2, v4)); a0 = fmaf(f.x, w4, a0); a1 = fmaf(f.y, w4, a1);
      f = __half22float2(__builtin_bit_cast(__half2, v5)); a0 = fmaf(f.x, w5, a0); a1 = fmaf(f.y, w5, a1);
      f = __half22float2(__builtin_bit_cast(__half2, v6)); a0 = fmaf(f.x, w6, a0); a1 = fmaf(f.y, w6, a1);
      f = __half22float2(__builtin_bit_cast(__half2, v7)); a0 = fmaf(f.x, w7, a0); a1 = fmaf(f.y, w7, a1);
    }
    uint vw = t2u[(size_t)wid * 64 + lane];
    float2 fw = __half22float2(__builtin_bit_cast(__half2, vw));
    float sc = SCALE ? dd : 1.f;
    a0 = fmaf(fw.x, sc, a0); a1 = fmaf(fw.y, sc, a1);
  }
  float2 b = ((const float2*)bias)[lane];
  float r0 = fmaf(a0, dd, b.x);
  float r1 = fmaf(a1, dd, b.y);
  r0 = r0 > 0.f ? r0 : expm1f(r0);
  r1 = r1 > 0.f ? r1 : expm1f(r1);
  if (!LAST) {
    half2v o = {(_Float16)r0, (_Float16)r1};
    ((uint*)hout)[(size_t)wid * 64 + lane] = __builtin_bit_cast(uint, o);
  } else {
    float2 wv = ((const float2*)Wl)[lane];
    float s = r0 * wv.x + r1 * wv.y;
    s += __shfl_down(s, 32);
    s += __shfl_down(s, 16);
    s += __shfl_down(s, 8);
    s += __shfl_down(s, 4);
    s += __shfl_down(s, 2);
    s += __shfl_down(s, 1);
    if (lane == 0) out[wid] = s + bl[0];
  }
}

extern "C" void kernel_launch(void* const* d_in, const int* in_sizes, int n_in,
                              void* d_out, int out_size, void* d_ws, size_t ws_size,
                              hipStream_t stream) {
  const int N = in_sizes[0] / 128;
  const int E = in_sizes[5] / 2;
  const int NBINS = (N + 255) >> 8;  // 196
  const float* x  = (const float*)d_in[0];
  const float* Ws = (const float*)d_in[1];
  const float* bs = (const float*)d_in[2];
  const float* Wl = (const float*)d_in[3];
  const float* bl = (const float*)d_in[4];
  const int* ei   = (const int*)d_in[5];
  const int* srcA = ei;
  const int* dstA = ei + E;
  float* out = (float*)d_out;

  char* w = (char*)d_ws;
  size_t o = 0;
  auto alloc = [&](size_t bytes) -> void* {
    void* p = w + o;
    o += (bytes + 255) & ~(size_t)255;
    return p;
  };
  int*       cnt    = (int*)      alloc((size_t)N * 4);
  int*       binCnt = (int*)      alloc((size_t)(NBINS + 32) * 4);  // + 16 leaf + 1 root (pad)
  uint*      binBuf = (uint*)     alloc((size_t)NBINS * BCAP * 4);
  ushort*    colidx = (ushort*)   alloc((size_t)NBINS * 256 * CAP * 2);
  _Float16*  hbuf   = (_Float16*) alloc((size_t)N * 128 * 2);
  _Float16*  tbuf   = (_Float16*) alloc((size_t)N * 128 * 2);
  half8*     W16    = (half8*)    alloc((size_t)3 * 2048 * 16);
  int*       bar    = binCnt + NBINS;  // [0..15] leaves, [16] root
  (void)ws_size; (void)n_in; (void)out_size;

  const int nbW = (N + 3) / 4;
  const int gemmGrid = (N + 63) / 64;      // 782
  const int npart1 = (E + EPB - 1) / EPB;  // 391

  cvtw_k<<<(3 * 2048 + TPB - 1) / TPB, TPB, 0, stream>>>(Ws, W16, binCnt, NBINS + 32);
  prep_k<<<PREPB, TPB, 0, stream>>>(x, W16, srcA, dstA, binCnt, binBuf, colidx, cnt, bar,
                                    tbuf, E, N, NBINS, npart1, gemmGrid);
  agg_k<true, false><<<nbW, TPB, 0, stream>>>((const uint*)tbuf, cnt, colidx, bs, hbuf,
                                              nullptr, nullptr, nullptr, N);
  gemm_k<<<gemmGrid, TPB, 0, stream>>>(hbuf, W16 + 2048, cnt, tbuf, N);
  agg_k<false, false><<<nbW, TPB, 0, stream>>>((const uint*)tbuf, cnt, colidx, bs + 128, hbuf,
                                               nullptr, nullptr, nullptr, N);
  gemm_k<<<gemmGrid, TPB, 0, stream>>>(hbuf, W16 + 4096, cnt, tbuf, N);
  agg_k<false, true><<<nbW, TPB, 0, stream>>>((const uint*)tbuf, cnt, colidx, bs + 256, nullptr,
                                              Wl, bl, out, N);
}

// Round 13
// 244.063 us; speedup vs baseline: 1.6424x; 1.6424x over previous
//
#include <hip/hip_runtime.h>
#include <hip/hip_fp16.h>

#define TPB 256
#define CAP 64    // bucket capacity per node; P(deg>64) ~ 1e-14 at Poisson(16)
#define EPB 2048  // edges per part1 block
#define BCAP 6144 // edge capacity per bin region

typedef _Float16 half8 __attribute__((ext_vector_type(8)));
typedef _Float16 half2v __attribute__((ext_vector_type(2)));
typedef float floatx4 __attribute__((ext_vector_type(4)));

// ---------- fused: part1 radix-partition (blocks < npart1) + W conversion (rest) ----------
__global__ __launch_bounds__(TPB) void part1cvtw_k(const int* __restrict__ src, const int* __restrict__ dst,
                                                   int* __restrict__ binCnt, uint* __restrict__ binBuf,
                                                   const float* __restrict__ W, half8* __restrict__ W16,
                                                   int E, int nbins, int npart1) {
  __shared__ int hist[256];
  __shared__ int offs[256];
  const int tid = threadIdx.x;
  if ((int)blockIdx.x >= npart1) {
    // W conversion: 24 blocks x 256 threads cover 3*2048 fragments
    int j = ((int)blockIdx.x - npart1) * TPB + tid;
    if (j < 3 * 2048) {
      int layer = j >> 11;
      int r = j & 2047;
      int kf = r >> 7;
      int nn = r & 127;
      const float* Wl = W + (size_t)layer * 16384;
      half8 v;
#pragma unroll
      for (int jj = 0; jj < 8; jj++) v[jj] = (_Float16)Wl[(kf * 8 + jj) * 128 + nn];
      W16[j] = v;
    }
    return;
  }
  const int bb = blockIdx.x * EPB;
  hist[tid] = 0;
  __syncthreads();
  int sv[8], dv[8];
#pragma unroll
  for (int k = 0; k < 8; k++) {
    int i = bb + tid + k * TPB;
    if (i < E) { sv[k] = src[i]; dv[k] = dst[i]; }
    else { sv[k] = 0; dv[k] = -1; }
  }
#pragma unroll
  for (int k = 0; k < 8; k++)
    if (dv[k] >= 0) atomicAdd(&hist[dv[k] >> 8], 1);
  __syncthreads();
  if (tid < nbins) offs[tid] = hist[tid] ? atomicAdd(&binCnt[tid], hist[tid]) : 0;
  __syncthreads();
#pragma unroll
  for (int k = 0; k < 8; k++) {
    if (dv[k] >= 0) {
      int b = dv[k] >> 8;
      int r = atomicAdd(&offs[b], 1);  // absolute offset within bin (seeded with base)
      if (r < BCAP)
        binBuf[(size_t)b * BCAP + r] = ((uint)(dv[k] & 255) << 16) | (uint)(ushort)sv[k];
    }
  }
}

// ---------- fused: part2 bucket-build (blocks < nbins) + raw gemm0 t=x@W0 (rest) ----------
// Both halves depend only on the previous dispatch (part1 / cvtw) - no intra-kernel ordering needed.
__global__ __launch_bounds__(TPB) void part2gemm0_k(const int* __restrict__ binCnt, const uint* __restrict__ binBuf,
                                                    ushort* __restrict__ colidx, int* __restrict__ cnt,
                                                    const float* __restrict__ x, const half8* __restrict__ W16,
                                                    _Float16* __restrict__ t, int n, int nbins) {
  __shared__ __align__(16) ushort lb[256 * CAP];  // 32 KB
  __shared__ int lc[256];
  const int tid = threadIdx.x;
  if ((int)blockIdx.x < nbins) {
    const int b = blockIdx.x;
    lc[tid] = 0;
    __syncthreads();
    int count = binCnt[b];
    if (count > BCAP) count = BCAP;
    for (int i = tid; i < count; i += TPB) {
      uint p = binBuf[(size_t)b * BCAP + i];
      int dl = (p >> 16) & 255;
      int s = p & 0xFFFF;
      int r = atomicAdd(&lc[dl], 1);
      if (r < CAP) lb[(dl << 6) + r] = (ushort)s;
    }
    __syncthreads();
    uint4* gb = (uint4*)(colidx + (size_t)b * 256 * CAP);
    const uint4* sb = (const uint4*)lb;
#pragma unroll
    for (int k = 0; k < 8; k++) gb[tid + TPB * k] = sb[tid + TPB * k];
    int node = b * 256 + tid;
    if (node < n) cnt[node] = lc[tid];
    return;
  }
  // gemm0 tile: raw t = x @ W0 (cnt not ready; agg0 applies dis per edge)
  const int g = (int)blockIdx.x - nbins;
  const int lane = tid & 63;
  const int wv = tid >> 6;
  const int m16 = lane & 15;
  const int q = lane >> 4;
  const int r0 = g * 64;
  if (r0 >= n) return;
  half8 bfr[2][4];
#pragma unroll
  for (int nt2 = 0; nt2 < 2; nt2++) {
    const int ncol = 16 * (2 * wv + nt2) + m16;
#pragma unroll
    for (int kit = 0; kit < 4; kit++)
      bfr[nt2][kit] = W16[(kit * 4 + q) * 128 + ncol];
  }
  floatx4 acc[2][4];
#pragma unroll
  for (int a = 0; a < 2; a++)
#pragma unroll
    for (int b2 = 0; b2 < 4; b2++) acc[a][b2] = (floatx4){0.f, 0.f, 0.f, 0.f};
#pragma unroll
  for (int kit = 0; kit < 4; kit++) {
    half8 af[4];
#pragma unroll
    for (int rt = 0; rt < 4; rt++) {
      int row = r0 + 16 * rt + m16;
      half8 a = {0, 0, 0, 0, 0, 0, 0, 0};
      if (row < n) {
        const float4* hp = (const float4*)(x + (size_t)row * 128 + 32 * kit + 8 * q);
        float4 p0 = hp[0], p1 = hp[1];
        a = half8{(_Float16)p0.x, (_Float16)p0.y, (_Float16)p0.z, (_Float16)p0.w,
                  (_Float16)p1.x, (_Float16)p1.y, (_Float16)p1.z, (_Float16)p1.w};
      }
      af[rt] = a;
    }
#pragma unroll
    for (int rt = 0; rt < 4; rt++)
#pragma unroll
      for (int nt2 = 0; nt2 < 2; nt2++)
        acc[nt2][rt] = __builtin_amdgcn_mfma_f32_16x16x32_f16(af[rt], bfr[nt2][kit], acc[nt2][rt], 0, 0, 0);
  }
#pragma unroll
  for (int rt = 0; rt < 4; rt++) {
#pragma unroll
    for (int reg = 0; reg < 4; reg++) {
      int row = r0 + 16 * rt + 4 * q + reg;
      if (row < n) {
#pragma unroll
        for (int nt2 = 0; nt2 < 2; nt2++) {
          int col = 16 * (2 * wv + nt2) + m16;
          t[(size_t)row * 128 + col] = (_Float16)acc[nt2][rt][reg];
        }
      }
    }
  }
}

// ---------- t = rsqrt(cnt[row]+1) * (h @ W), fp16, layers 1-2 ----------
__global__ __launch_bounds__(TPB) void gemm_k(const _Float16* __restrict__ h, const half8* __restrict__ W16,
                                              const int* __restrict__ cnt, _Float16* __restrict__ t, int n) {
  const int tid = threadIdx.x;
  const int lane = tid & 63;
  const int wv = tid >> 6;
  const int m16 = lane & 15;
  const int q = lane >> 4;
  const int r0 = blockIdx.x * 64;
  half8 bfr[2][4];
#pragma unroll
  for (int nt2 = 0; nt2 < 2; nt2++) {
    const int ncol = 16 * (2 * wv + nt2) + m16;
#pragma unroll
    for (int kit = 0; kit < 4; kit++)
      bfr[nt2][kit] = W16[(kit * 4 + q) * 128 + ncol];
  }
  floatx4 acc[2][4];
#pragma unroll
  for (int a = 0; a < 2; a++)
#pragma unroll
    for (int b = 0; b < 4; b++) acc[a][b] = (floatx4){0.f, 0.f, 0.f, 0.f};
#pragma unroll
  for (int kit = 0; kit < 4; kit++) {
    half8 af[4];
#pragma unroll
    for (int rt = 0; rt < 4; rt++) {
      int row = r0 + 16 * rt + m16;
      half8 a = {0, 0, 0, 0, 0, 0, 0, 0};
      if (row < n) a = *(const half8*)(h + (size_t)row * 128 + 32 * kit + 8 * q);
      af[rt] = a;
    }
#pragma unroll
    for (int rt = 0; rt < 4; rt++)
#pragma unroll
      for (int nt2 = 0; nt2 < 2; nt2++)
        acc[nt2][rt] = __builtin_amdgcn_mfma_f32_16x16x32_f16(af[rt], bfr[nt2][kit], acc[nt2][rt], 0, 0, 0);
  }
#pragma unroll
  for (int rt = 0; rt < 4; rt++) {
#pragma unroll
    for (int reg = 0; reg < 4; reg++) {
      int row = r0 + 16 * rt + 4 * q + reg;
      if (row < n) {
        float dsc = rsqrtf((float)(cnt[row] + 1));
#pragma unroll
        for (int nt2 = 0; nt2 < 2; nt2++) {
          int col = 16 * (2 * wv + nt2) + m16;
          t[(size_t)row * 128 + col] = (_Float16)(acc[nt2][rt][reg] * dsc);
        }
      }
    }
  }
}

// ---------- aggregation (SCALE: layer-0 t raw -> per-edge rsqrt; LAST: fused projection) ----------
#define GATH(k)  int s##k = __builtin_amdgcn_readlane(myIdx, k); uint v##k = t2u[(size_t)s##k * 64 + lane]; \
                 float w##k = SCALE ? rsqrtf((float)(cnt[s##k] + 1)) : 1.f;
#define CONS(k)  { float2 f_ = __half22float2(__builtin_bit_cast(__half2, v##k)); \
                   if (SCALE) { a0 = fmaf(f_.x, w##k, a0); a1 = fmaf(f_.y, w##k, a1); } \
                   else { a0 += f_.x; a1 += f_.y; } }

template <bool SCALE, bool LAST>
__global__ __launch_bounds__(TPB) void agg_k(const uint* __restrict__ t2u, const int* __restrict__ cnt,
                                             const ushort* __restrict__ colidx,
                                             const float* __restrict__ bias, _Float16* __restrict__ hout,
                                             const float* __restrict__ Wl, const float* __restrict__ bl,
                                             float* __restrict__ out, int n) {
  int wid = (blockIdx.x * TPB + threadIdx.x) >> 6;
  int lane = threadIdx.x & 63;
  if (wid >= n) return;
  int m = cnt[wid];
  float dd = rsqrtf((float)(m + 1));
  if (m > CAP) m = CAP;
  const size_t base = (size_t)wid * CAP;
  float a0 = 0.f, a1 = 0.f;
  if (m <= 32) {
    int myIdx = wid;  // pad slots -> self row (compensated below)
    if (lane < m) myIdx = (int)colidx[base + lane];
    if (m <= 16) {
      GATH(0) GATH(1) GATH(2) GATH(3) GATH(4) GATH(5) GATH(6) GATH(7)
      GATH(8) GATH(9) GATH(10) GATH(11) GATH(12) GATH(13) GATH(14) GATH(15)
      uint vw = t2u[(size_t)wid * 64 + lane];
      CONS(0) CONS(1) CONS(2) CONS(3) CONS(4) CONS(5) CONS(6) CONS(7)
      CONS(8) CONS(9) CONS(10) CONS(11) CONS(12) CONS(13) CONS(14) CONS(15)
      float2 fw = __half22float2(__builtin_bit_cast(__half2, vw));
      float sc = SCALE ? dd * (float)(m - 15) : (float)(m - 15);
      a0 = fmaf(fw.x, sc, a0); a1 = fmaf(fw.y, sc, a1);
    } else {
      GATH(0) GATH(1) GATH(2) GATH(3) GATH(4) GATH(5) GATH(6) GATH(7)
      GATH(8) GATH(9) GATH(10) GATH(11) GATH(12) GATH(13) GATH(14) GATH(15)
      GATH(16) GATH(17) GATH(18) GATH(19) GATH(20) GATH(21) GATH(22) GATH(23)
      GATH(24) GATH(25) GATH(26) GATH(27) GATH(28) GATH(29) GATH(30) GATH(31)
      uint vw = t2u[(size_t)wid * 64 + lane];
      CONS(0) CONS(1) CONS(2) CONS(3) CONS(4) CONS(5) CONS(6) CONS(7)
      CONS(8) CONS(9) CONS(10) CONS(11) CONS(12) CONS(13) CONS(14) CONS(15)
      CONS(16) CONS(17) CONS(18) CONS(19) CONS(20) CONS(21) CONS(22) CONS(23)
      CONS(24) CONS(25) CONS(26) CONS(27) CONS(28) CONS(29) CONS(30) CONS(31)
      float2 fw = __half22float2(__builtin_bit_cast(__half2, vw));
      float sc = SCALE ? dd * (float)(m - 31) : (float)(m - 31);
      a0 = fmaf(fw.x, sc, a0); a1 = fmaf(fw.y, sc, a1);
    }
  } else {  // 32 < m <= 64, rare
    int myIdx = 0;
    if (lane < m) myIdx = (int)colidx[base + lane];
    for (int e = 0; e < m; e += 8) {
      int s0 = __builtin_amdgcn_readlane(myIdx, e + 0);
      int s1 = __builtin_amdgcn_readlane(myIdx, e + 1);
      int s2 = __builtin_amdgcn_readlane(myIdx, e + 2);
      int s3 = __builtin_amdgcn_readlane(myIdx, e + 3);
      int s4 = __builtin_amdgcn_readlane(myIdx, e + 4);
      int s5 = __builtin_amdgcn_readlane(myIdx, e + 5);
      int s6 = __builtin_amdgcn_readlane(myIdx, e + 6);
      int s7 = __builtin_amdgcn_readlane(myIdx, e + 7);
      uint v0 = t2u[(size_t)s0 * 64 + lane];
      uint v1 = t2u[(size_t)s1 * 64 + lane];
      uint v2 = t2u[(size_t)s2 * 64 + lane];
      uint v3 = t2u[(size_t)s3 * 64 + lane];
      uint v4 = t2u[(size_t)s4 * 64 + lane];
      uint v5 = t2u[(size_t)s5 * 64 + lane];
      uint v6 = t2u[(size_t)s6 * 64 + lane];
      uint v7 = t2u[(size_t)s7 * 64 + lane];
      v1 = (e + 1 < m) ? v1 : 0u;
      v2 = (e + 2 < m) ? v2 : 0u;
      v3 = (e + 3 < m) ? v3 : 0u;
      v4 = (e + 4 < m) ? v4 : 0u;
      v5 = (e + 5 < m) ? v5 : 0u;
      v6 = (e + 6 < m) ? v6 : 0u;
      v7 = (e + 7 < m) ? v7 : 0u;
      float w0 = SCALE ? rsqrtf((float)(cnt[s0] + 1)) : 1.f;
      float w1 = SCALE ? rsqrtf((float)(cnt[s1] + 1)) : 1.f;
      float w2 = SCALE ? rsqrtf((float)(cnt[s2] + 1)) : 1.f;
      float w3 = SCALE ? rsqrtf((float)(cnt[s3] + 1)) : 1.f;
      float w4 = SCALE ? rsqrtf((float)(cnt[s4] + 1)) : 1.f;
      float w5 = SCALE ? rsqrtf((float)(cnt[s5] + 1)) : 1.f;
      float w6 = SCALE ? rsqrtf((float)(cnt[s6] + 1)) : 1.f;
      float w7 = SCALE ? rsqrtf((float)(cnt[s7] + 1)) : 1.f;
      float2 f;
      f = __half22float2(__builtin_bit_cast(__half2, v0)); a0 = fmaf(f.x, w0, a0); a1 = fmaf(f.y, w0, a1);
      f = __half22float2(__builtin_bit_cast(__half2, v1)); a0 = fmaf(f.x, w1, a0); a1 = fmaf(f.y, w1, a1);
      f = __half22float2(__builtin_bit_cast(__half2, v2)); a0 = fmaf(f.x, w2, a0); a1 = fmaf(f.y, w2, a1);
      f = __half22float2(__builtin_bit_cast(__half2, v3)); a0 = fmaf(f.x, w3, a0); a1 = fmaf(f.y, w3, a1);
      f = __half22float2(__builtin_bit_cast(__half2, v4)); a0 = fmaf(f.x, w4, a0); a1 = fmaf(f.y, w4, a1);
      f = __half22float2(__builtin_bit_cast(__half2, v5)); a0 = fmaf(f.x, w5, a0); a1 = fmaf(f.y, w5, a1);
      f = __half22float2(__builtin_bit_cast(__half2, v6)); a0 = fmaf(f.x, w6, a0); a1 = fmaf(f.y, w6, a1);
      f = __half22float2(__builtin_bit_cast(__half2, v7)); a0 = fmaf(f.x, w7, a0); a1 = fmaf(f.y, w7, a1);
    }
    uint vw = t2u[(size_t)wid * 64 + lane];
    float2 fw = __half22float2(__builtin_bit_cast(__half2, vw));
    float sc = SCALE ? dd : 1.f;
    a0 = fmaf(fw.x, sc, a0); a1 = fmaf(fw.y, sc, a1);
  }
  float2 b = ((const float2*)bias)[lane];
  float r0 = fmaf(a0, dd, b.x);
  float r1 = fmaf(a1, dd, b.y);
  r0 = r0 > 0.f ? r0 : expm1f(r0);
  r1 = r1 > 0.f ? r1 : expm1f(r1);
  if (!LAST) {
    half2v o = {(_Float16)r0, (_Float16)r1};
    ((uint*)hout)[(size_t)wid * 64 + lane] = __builtin_bit_cast(uint, o);
  } else {
    float2 wv = ((const float2*)Wl)[lane];
    float s = r0 * wv.x + r1 * wv.y;
    s += __shfl_down(s, 32);
    s += __shfl_down(s, 16);
    s += __shfl_down(s, 8);
    s += __shfl_down(s, 4);
    s += __shfl_down(s, 2);
    s += __shfl_down(s, 1);
    if (lane == 0) out[wid] = s + bl[0];
  }
}

extern "C" void kernel_launch(void* const* d_in, const int* in_sizes, int n_in,
                              void* d_out, int out_size, void* d_ws, size_t ws_size,
                              hipStream_t stream) {
  const int N = in_sizes[0] / 128;
  const int E = in_sizes[5] / 2;
  const int NBINS = (N + 255) >> 8;  // 196
  const float* x  = (const float*)d_in[0];
  const float* Ws = (const float*)d_in[1];
  const float* bs = (const float*)d_in[2];
  const float* Wl = (const float*)d_in[3];
  const float* bl = (const float*)d_in[4];
  const int* ei   = (const int*)d_in[5];
  const int* srcA = ei;
  const int* dstA = ei + E;
  float* out = (float*)d_out;

  char* w = (char*)d_ws;
  size_t o = 0;
  auto alloc = [&](size_t bytes) -> void* {
    void* p = w + o;
    o += (bytes + 255) & ~(size_t)255;
    return p;
  };
  int*       cnt    = (int*)      alloc((size_t)N * 4);
  int*       binCnt = (int*)      alloc((size_t)NBINS * 4);
  uint*      binBuf = (uint*)     alloc((size_t)NBINS * BCAP * 4);
  ushort*    colidx = (ushort*)   alloc((size_t)NBINS * 256 * CAP * 2);
  _Float16*  hbuf   = (_Float16*) alloc((size_t)N * 128 * 2);
  _Float16*  tbuf   = (_Float16*) alloc((size_t)N * 128 * 2);
  half8*     W16    = (half8*)    alloc((size_t)3 * 2048 * 16);
  (void)ws_size; (void)n_in; (void)out_size;

  const int nbW = (N + 3) / 4;
  const int gemmGrid = (N + 63) / 64;       // 782
  const int npart1 = (E + EPB - 1) / EPB;   // 391
  const int ncvtw = (3 * 2048 + TPB - 1) / TPB;  // 24

  hipMemsetAsync(binCnt, 0, (size_t)NBINS * 4, stream);
  part1cvtw_k<<<npart1 + ncvtw, TPB, 0, stream>>>(srcA, dstA, binCnt, binBuf, Ws, W16,
                                                  E, NBINS, npart1);
  part2gemm0_k<<<NBINS + gemmGrid, TPB, 0, stream>>>(binCnt, binBuf, colidx, cnt,
                                                     x, W16, tbuf, N, NBINS);
  agg_k<true, false><<<nbW, TPB, 0, stream>>>((const uint*)tbuf, cnt, colidx, bs, hbuf,
                                              nullptr, nullptr, nullptr, N);
  gemm_k<<<gemmGrid, TPB, 0, stream>>>(hbuf, W16 + 2048, cnt, tbuf, N);
  agg_k<false, false><<<nbW, TPB, 0, stream>>>((const uint*)tbuf, cnt, colidx, bs + 128, hbuf,
                                               nullptr, nullptr, nullptr, N);
  gemm_k<<<gemmGrid, TPB, 0, stream>>>(hbuf, W16 + 4096, cnt, tbuf, N);
  agg_k<false, true><<<nbW, TPB, 0, stream>>>((const uint*)tbuf, cnt, colidx, bs + 256, nullptr,
                                              Wl, bl, out, N);
}

// Round 14
// 237.035 us; speedup vs baseline: 1.6911x; 1.0296x over previous
//
#include <hip/hip_runtime.h>
#include <hip/hip_fp16.h>

#define TPB 256
#define CAP 64    // bucket capacity per node; P(deg>64) ~ 1e-14 at Poisson(16)
#define EPB 2048  // edges per part1 block
#define BCAP 6144 // edge capacity per bin region

typedef _Float16 half8 __attribute__((ext_vector_type(8)));
typedef _Float16 half2v __attribute__((ext_vector_type(2)));
typedef float floatx4 __attribute__((ext_vector_type(4)));

// ---------- fused: part1 radix-partition (blocks < npart1) + W conversion (rest) ----------
__global__ __launch_bounds__(TPB) void part1cvtw_k(const int* __restrict__ src, const int* __restrict__ dst,
                                                   int* __restrict__ binCnt, uint* __restrict__ binBuf,
                                                   const float* __restrict__ W, half8* __restrict__ W16,
                                                   int E, int nbins, int npart1) {
  __shared__ int hist[256];
  __shared__ int offs[256];
  const int tid = threadIdx.x;
  if ((int)blockIdx.x >= npart1) {
    int j = ((int)blockIdx.x - npart1) * TPB + tid;
    if (j < 3 * 2048) {
      int layer = j >> 11;
      int r = j & 2047;
      int kf = r >> 7;
      int nn = r & 127;
      const float* Wl = W + (size_t)layer * 16384;
      half8 v;
#pragma unroll
      for (int jj = 0; jj < 8; jj++) v[jj] = (_Float16)Wl[(kf * 8 + jj) * 128 + nn];
      W16[j] = v;
    }
    return;
  }
  const int bb = blockIdx.x * EPB;
  hist[tid] = 0;
  __syncthreads();
  int sv[8], dv[8];
#pragma unroll
  for (int k = 0; k < 8; k++) {
    int i = bb + tid + k * TPB;
    if (i < E) { sv[k] = src[i]; dv[k] = dst[i]; }
    else { sv[k] = 0; dv[k] = -1; }
  }
#pragma unroll
  for (int k = 0; k < 8; k++)
    if (dv[k] >= 0) atomicAdd(&hist[dv[k] >> 8], 1);
  __syncthreads();
  if (tid < nbins) offs[tid] = hist[tid] ? atomicAdd(&binCnt[tid], hist[tid]) : 0;
  __syncthreads();
#pragma unroll
  for (int k = 0; k < 8; k++) {
    if (dv[k] >= 0) {
      int b = dv[k] >> 8;
      int r = atomicAdd(&offs[b], 1);
      if (r < BCAP)
        binBuf[(size_t)b * BCAP + r] = ((uint)(dv[k] & 255) << 16) | (uint)(ushort)sv[k];
    }
  }
}

// ---------- fused: part2 bucket-build + dis (blocks < nbins) + raw gemm0 t=x@W0 (rest) ----------
__global__ __launch_bounds__(TPB) void part2gemm0_k(const int* __restrict__ binCnt, const uint* __restrict__ binBuf,
                                                    ushort* __restrict__ colidx, int* __restrict__ cnt,
                                                    float* __restrict__ dis,
                                                    const float* __restrict__ x, const half8* __restrict__ W16,
                                                    _Float16* __restrict__ t, int n, int nbins) {
  __shared__ __align__(16) ushort lb[256 * CAP];  // 32 KB
  __shared__ int lc[256];
  const int tid = threadIdx.x;
  if ((int)blockIdx.x < nbins) {
    const int b = blockIdx.x;
    lc[tid] = 0;
    __syncthreads();
    int count = binCnt[b];
    if (count > BCAP) count = BCAP;
    for (int i = tid; i < count; i += TPB) {
      uint p = binBuf[(size_t)b * BCAP + i];
      int dl = (p >> 16) & 255;
      int s = p & 0xFFFF;
      int r = atomicAdd(&lc[dl], 1);
      if (r < CAP) lb[(dl << 6) + r] = (ushort)s;
    }
    __syncthreads();
    uint4* gb = (uint4*)(colidx + (size_t)b * 256 * CAP);
    const uint4* sb = (const uint4*)lb;
#pragma unroll
    for (int k = 0; k < 8; k++) gb[tid + TPB * k] = sb[tid + TPB * k];
    int node = b * 256 + tid;
    if (node < n) {
      cnt[node] = lc[tid];
      dis[node] = rsqrtf((float)(lc[tid] + 1));
    }
    return;
  }
  // gemm0 tile: raw t = x @ W0 (cnt/dis not ready; agg0 applies dis per edge)
  const int g = (int)blockIdx.x - nbins;
  const int lane = tid & 63;
  const int wv = tid >> 6;
  const int m16 = lane & 15;
  const int q = lane >> 4;
  const int r0 = g * 64;
  if (r0 >= n) return;
  half8 bfr[2][4];
#pragma unroll
  for (int nt2 = 0; nt2 < 2; nt2++) {
    const int ncol = 16 * (2 * wv + nt2) + m16;
#pragma unroll
    for (int kit = 0; kit < 4; kit++)
      bfr[nt2][kit] = W16[(kit * 4 + q) * 128 + ncol];
  }
  floatx4 acc[2][4];
#pragma unroll
  for (int a = 0; a < 2; a++)
#pragma unroll
    for (int b2 = 0; b2 < 4; b2++) acc[a][b2] = (floatx4){0.f, 0.f, 0.f, 0.f};
#pragma unroll
  for (int kit = 0; kit < 4; kit++) {
    half8 af[4];
#pragma unroll
    for (int rt = 0; rt < 4; rt++) {
      int row = r0 + 16 * rt + m16;
      half8 a = {0, 0, 0, 0, 0, 0, 0, 0};
      if (row < n) {
        const float4* hp = (const float4*)(x + (size_t)row * 128 + 32 * kit + 8 * q);
        float4 p0 = hp[0], p1 = hp[1];
        a = half8{(_Float16)p0.x, (_Float16)p0.y, (_Float16)p0.z, (_Float16)p0.w,
                  (_Float16)p1.x, (_Float16)p1.y, (_Float16)p1.z, (_Float16)p1.w};
      }
      af[rt] = a;
    }
#pragma unroll
    for (int rt = 0; rt < 4; rt++)
#pragma unroll
      for (int nt2 = 0; nt2 < 2; nt2++)
        acc[nt2][rt] = __builtin_amdgcn_mfma_f32_16x16x32_f16(af[rt], bfr[nt2][kit], acc[nt2][rt], 0, 0, 0);
  }
#pragma unroll
  for (int rt = 0; rt < 4; rt++) {
#pragma unroll
    for (int reg = 0; reg < 4; reg++) {
      int row = r0 + 16 * rt + 4 * q + reg;
      if (row < n) {
#pragma unroll
        for (int nt2 = 0; nt2 < 2; nt2++) {
          int col = 16 * (2 * wv + nt2) + m16;
          t[(size_t)row * 128 + col] = (_Float16)acc[nt2][rt][reg];
        }
      }
    }
  }
}

// ---------- t = dis[row] * (h @ W), fp16, layers 1-2 ----------
__global__ __launch_bounds__(TPB) void gemm_k(const _Float16* __restrict__ h, const half8* __restrict__ W16,
                                              const float* __restrict__ dis, _Float16* __restrict__ t, int n) {
  const int tid = threadIdx.x;
  const int lane = tid & 63;
  const int wv = tid >> 6;
  const int m16 = lane & 15;
  const int q = lane >> 4;
  const int r0 = blockIdx.x * 64;
  half8 bfr[2][4];
#pragma unroll
  for (int nt2 = 0; nt2 < 2; nt2++) {
    const int ncol = 16 * (2 * wv + nt2) + m16;
#pragma unroll
    for (int kit = 0; kit < 4; kit++)
      bfr[nt2][kit] = W16[(kit * 4 + q) * 128 + ncol];
  }
  floatx4 acc[2][4];
#pragma unroll
  for (int a = 0; a < 2; a++)
#pragma unroll
    for (int b = 0; b < 4; b++) acc[a][b] = (floatx4){0.f, 0.f, 0.f, 0.f};
#pragma unroll
  for (int kit = 0; kit < 4; kit++) {
    half8 af[4];
#pragma unroll
    for (int rt = 0; rt < 4; rt++) {
      int row = r0 + 16 * rt + m16;
      half8 a = {0, 0, 0, 0, 0, 0, 0, 0};
      if (row < n) a = *(const half8*)(h + (size_t)row * 128 + 32 * kit + 8 * q);
      af[rt] = a;
    }
#pragma unroll
    for (int rt = 0; rt < 4; rt++)
#pragma unroll
      for (int nt2 = 0; nt2 < 2; nt2++)
        acc[nt2][rt] = __builtin_amdgcn_mfma_f32_16x16x32_f16(af[rt], bfr[nt2][kit], acc[nt2][rt], 0, 0, 0);
  }
#pragma unroll
  for (int rt = 0; rt < 4; rt++) {
#pragma unroll
    for (int reg = 0; reg < 4; reg++) {
      int row = r0 + 16 * rt + 4 * q + reg;
      if (row < n) {
        float dsc = dis[row];
#pragma unroll
        for (int nt2 = 0; nt2 < 2; nt2++) {
          int col = 16 * (2 * wv + nt2) + m16;
          t[(size_t)row * 128 + col] = (_Float16)(acc[nt2][rt][reg] * dsc);
        }
      }
    }
  }
}

// ---------- aggregation (SCALE: layer-0 t raw -> per-edge dis[s] scalar load; LAST: fused proj) ----------
#define GATH(k)  int s##k = __builtin_amdgcn_readlane(myIdx, k); uint v##k = t2u[(size_t)s##k * 64 + lane]; \
                 float w##k = SCALE ? dis[s##k] : 1.f;
#define CONS(k)  { float2 f_ = __half22float2(__builtin_bit_cast(__half2, v##k)); \
                   if (SCALE) { a0 = fmaf(f_.x, w##k, a0); a1 = fmaf(f_.y, w##k, a1); } \
                   else { a0 += f_.x; a1 += f_.y; } }

template <bool SCALE, bool LAST>
__global__ __launch_bounds__(TPB) void agg_k(const uint* __restrict__ t2u, const int* __restrict__ cnt,
                                             const float* __restrict__ dis,
                                             const ushort* __restrict__ colidx,
                                             const float* __restrict__ bias, _Float16* __restrict__ hout,
                                             const float* __restrict__ Wl, const float* __restrict__ bl,
                                             float* __restrict__ out, int n) {
  int wid = (blockIdx.x * TPB + threadIdx.x) >> 6;
  int lane = threadIdx.x & 63;
  if (wid >= n) return;
  int m = cnt[wid];
  float dd = dis[wid];
  if (m > CAP) m = CAP;
  const size_t base = (size_t)wid * CAP;
  float a0 = 0.f, a1 = 0.f;
  if (m <= 32) {
    int myIdx = wid;  // pad slots -> self row (compensated below)
    if (lane < m) myIdx = (int)colidx[base + lane];
    if (m <= 16) {
      GATH(0) GATH(1) GATH(2) GATH(3) GATH(4) GATH(5) GATH(6) GATH(7)
      GATH(8) GATH(9) GATH(10) GATH(11) GATH(12) GATH(13) GATH(14) GATH(15)
      uint vw = t2u[(size_t)wid * 64 + lane];
      CONS(0) CONS(1) CONS(2) CONS(3) CONS(4) CONS(5) CONS(6) CONS(7)
      CONS(8) CONS(9) CONS(10) CONS(11) CONS(12) CONS(13) CONS(14) CONS(15)
      float2 fw = __half22float2(__builtin_bit_cast(__half2, vw));
      float sc = SCALE ? dd * (float)(m - 15) : (float)(m - 15);
      a0 = fmaf(fw.x, sc, a0); a1 = fmaf(fw.y, sc, a1);
    } else {
      GATH(0) GATH(1) GATH(2) GATH(3) GATH(4) GATH(5) GATH(6) GATH(7)
      GATH(8) GATH(9) GATH(10) GATH(11) GATH(12) GATH(13) GATH(14) GATH(15)
      GATH(16) GATH(17) GATH(18) GATH(19) GATH(20) GATH(21) GATH(22) GATH(23)
      GATH(24) GATH(25) GATH(26) GATH(27) GATH(28) GATH(29) GATH(30) GATH(31)
      uint vw = t2u[(size_t)wid * 64 + lane];
      CONS(0) CONS(1) CONS(2) CONS(3) CONS(4) CONS(5) CONS(6) CONS(7)
      CONS(8) CONS(9) CONS(10) CONS(11) CONS(12) CONS(13) CONS(14) CONS(15)
      CONS(16) CONS(17) CONS(18) CONS(19) CONS(20) CONS(21) CONS(22) CONS(23)
      CONS(24) CONS(25) CONS(26) CONS(27) CONS(28) CONS(29) CONS(30) CONS(31)
      float2 fw = __half22float2(__builtin_bit_cast(__half2, vw));
      float sc = SCALE ? dd * (float)(m - 31) : (float)(m - 31);
      a0 = fmaf(fw.x, sc, a0); a1 = fmaf(fw.y, sc, a1);
    }
  } else {  // 32 < m <= 64, rare
    int myIdx = 0;
    if (lane < m) myIdx = (int)colidx[base + lane];
    for (int e = 0; e < m; e += 8) {
      int s0 = __builtin_amdgcn_readlane(myIdx, e + 0);
      int s1 = __builtin_amdgcn_readlane(myIdx, e + 1);
      int s2 = __builtin_amdgcn_readlane(myIdx, e + 2);
      int s3 = __builtin_amdgcn_readlane(myIdx, e + 3);
      int s4 = __builtin_amdgcn_readlane(myIdx, e + 4);
      int s5 = __builtin_amdgcn_readlane(myIdx, e + 5);
      int s6 = __builtin_amdgcn_readlane(myIdx, e + 6);
      int s7 = __builtin_amdgcn_readlane(myIdx, e + 7);
      uint v0 = t2u[(size_t)s0 * 64 + lane];
      uint v1 = t2u[(size_t)s1 * 64 + lane];
      uint v2 = t2u[(size_t)s2 * 64 + lane];
      uint v3 = t2u[(size_t)s3 * 64 + lane];
      uint v4 = t2u[(size_t)s4 * 64 + lane];
      uint v5 = t2u[(size_t)s5 * 64 + lane];
      uint v6 = t2u[(size_t)s6 * 64 + lane];
      uint v7 = t2u[(size_t)s7 * 64 + lane];
      v1 = (e + 1 < m) ? v1 : 0u;
      v2 = (e + 2 < m) ? v2 : 0u;
      v3 = (e + 3 < m) ? v3 : 0u;
      v4 = (e + 4 < m) ? v4 : 0u;
      v5 = (e + 5 < m) ? v5 : 0u;
      v6 = (e + 6 < m) ? v6 : 0u;
      v7 = (e + 7 < m) ? v7 : 0u;
      float w0 = SCALE ? dis[s0] : 1.f;
      float w1 = SCALE ? dis[s1] : 1.f;
      float w2 = SCALE ? dis[s2] : 1.f;
      float w3 = SCALE ? dis[s3] : 1.f;
      float w4 = SCALE ? dis[s4] : 1.f;
      float w5 = SCALE ? dis[s5] : 1.f;
      float w6 = SCALE ? dis[s6] : 1.f;
      float w7 = SCALE ? dis[s7] : 1.f;
      float2 f;
      f = __half22float2(__builtin_bit_cast(__half2, v0)); a0 = fmaf(f.x, w0, a0); a1 = fmaf(f.y, w0, a1);
      f = __half22float2(__builtin_bit_cast(__half2, v1)); a0 = fmaf(f.x, w1, a0); a1 = fmaf(f.y, w1, a1);
      f = __half22float2(__builtin_bit_cast(__half2, v2)); a0 = fmaf(f.x, w2, a0); a1 = fmaf(f.y, w2, a1);
      f = __half22float2(__builtin_bit_cast(__half2, v3)); a0 = fmaf(f.x, w3, a0); a1 = fmaf(f.y, w3, a1);
      f = __half22float2(__builtin_bit_cast(__half2, v4)); a0 = fmaf(f.x, w4, a0); a1 = fmaf(f.y, w4, a1);
      f = __half22float2(__builtin_bit_cast(__half2, v5)); a0 = fmaf(f.x, w5, a0); a1 = fmaf(f.y, w5, a1);
      f = __half22float2(__builtin_bit_cast(__half2, v6)); a0 = fmaf(f.x, w6, a0); a1 = fmaf(f.y, w6, a1);
      f = __half22float2(__builtin_bit_cast(__half2, v7)); a0 = fmaf(f.x, w7, a0); a1 = fmaf(f.y, w7, a1);
    }
    uint vw = t2u[(size_t)wid * 64 + lane];
    float2 fw = __half22float2(__builtin_bit_cast(__half2, vw));
    float sc = SCALE ? dd : 1.f;
    a0 = fmaf(fw.x, sc, a0); a1 = fmaf(fw.y, sc, a1);
  }
  float2 b = ((const float2*)bias)[lane];
  float r0 = fmaf(a0, dd, b.x);
  float r1 = fmaf(a1, dd, b.y);
  r0 = r0 > 0.f ? r0 : expm1f(r0);
  r1 = r1 > 0.f ? r1 : expm1f(r1);
  if (!LAST) {
    half2v o = {(_Float16)r0, (_Float16)r1};
    ((uint*)hout)[(size_t)wid * 64 + lane] = __builtin_bit_cast(uint, o);
  } else {
    float2 wv = ((const float2*)Wl)[lane];
    float s = r0 * wv.x + r1 * wv.y;
    s += __shfl_down(s, 32);
    s += __shfl_down(s, 16);
    s += __shfl_down(s, 8);
    s += __shfl_down(s, 4);
    s += __shfl_down(s, 2);
    s += __shfl_down(s, 1);
    if (lane == 0) out[wid] = s + bl[0];
  }
}

extern "C" void kernel_launch(void* const* d_in, const int* in_sizes, int n_in,
                              void* d_out, int out_size, void* d_ws, size_t ws_size,
                              hipStream_t stream) {
  const int N = in_sizes[0] / 128;
  const int E = in_sizes[5] / 2;
  const int NBINS = (N + 255) >> 8;  // 196
  const float* x  = (const float*)d_in[0];
  const float* Ws = (const float*)d_in[1];
  const float* bs = (const float*)d_in[2];
  const float* Wl = (const float*)d_in[3];
  const float* bl = (const float*)d_in[4];
  const int* ei   = (const int*)d_in[5];
  const int* srcA = ei;
  const int* dstA = ei + E;
  float* out = (float*)d_out;

  char* w = (char*)d_ws;
  size_t o = 0;
  auto alloc = [&](size_t bytes) -> void* {
    void* p = w + o;
    o += (bytes + 255) & ~(size_t)255;
    return p;
  };
  int*       cnt    = (int*)      alloc((size_t)N * 4);
  float*     dis    = (float*)    alloc((size_t)N * 4);
  int*       binCnt = (int*)      alloc((size_t)NBINS * 4);
  uint*      binBuf = (uint*)     alloc((size_t)NBINS * BCAP * 4);
  ushort*    colidx = (ushort*)   alloc((size_t)NBINS * 256 * CAP * 2);
  _Float16*  hbuf   = (_Float16*) alloc((size_t)N * 128 * 2);
  _Float16*  tbuf   = (_Float16*) alloc((size_t)N * 128 * 2);
  half8*     W16    = (half8*)    alloc((size_t)3 * 2048 * 16);
  (void)ws_size; (void)n_in; (void)out_size;

  const int nbW = (N + 3) / 4;
  const int gemmGrid = (N + 63) / 64;       // 782
  const int npart1 = (E + EPB - 1) / EPB;   // 391
  const int ncvtw = (3 * 2048 + TPB - 1) / TPB;  // 24

  hipMemsetAsync(binCnt, 0, (size_t)NBINS * 4, stream);
  part1cvtw_k<<<npart1 + ncvtw, TPB, 0, stream>>>(srcA, dstA, binCnt, binBuf, Ws, W16,
                                                  E, NBINS, npart1);
  part2gemm0_k<<<NBINS + gemmGrid, TPB, 0, stream>>>(binCnt, binBuf, colidx, cnt, dis,
                                                     x, W16, tbuf, N, NBINS);
  agg_k<true, false><<<nbW, TPB, 0, stream>>>((const uint*)tbuf, cnt, dis, colidx, bs, hbuf,
                                              nullptr, nullptr, nullptr, N);
  gemm_k<<<gemmGrid, TPB, 0, stream>>>(hbuf, W16 + 2048, dis, tbuf, N);
  agg_k<false, false><<<nbW, TPB, 0, stream>>>((const uint*)tbuf, cnt, dis, colidx, bs + 128, hbuf,
                                               nullptr, nullptr, nullptr, N);
  gemm_k<<<gemmGrid, TPB, 0, stream>>>(hbuf, W16 + 4096, dis, tbuf, N);
  agg_k<false, true><<<nbW, TPB, 0, stream>>>((const uint*)tbuf, cnt, dis, colidx, bs + 256, nullptr,
                                              Wl, bl, out, N);
}

// Round 15
// 236.189 us; speedup vs baseline: 1.6972x; 1.0036x over previous
//
#include <hip/hip_runtime.h>
#include <hip/hip_fp16.h>

#define TPB 256
#define CAP 64    // bucket capacity per node; P(deg>64) ~ 1e-14 at Poisson(16)
#define EPB 2048  // edges per part1 block
#define BCAP 6144 // edge capacity per bin region
#define HST 136   // LDS h-tile row stride in halves (272 B): 2-way (free) bank pattern

typedef _Float16 half8 __attribute__((ext_vector_type(8)));
typedef _Float16 half2v __attribute__((ext_vector_type(2)));
typedef float floatx4 __attribute__((ext_vector_type(4)));

// ---------- fused: part1 radix-partition (blocks < npart1) + W conversion (rest) ----------
__global__ __launch_bounds__(TPB) void part1cvtw_k(const int* __restrict__ src, const int* __restrict__ dst,
                                                   int* __restrict__ binCnt, uint* __restrict__ binBuf,
                                                   const float* __restrict__ W, half8* __restrict__ W16,
                                                   int E, int nbins, int npart1) {
  __shared__ int hist[256];
  __shared__ int offs[256];
  const int tid = threadIdx.x;
  if ((int)blockIdx.x >= npart1) {
    int j = ((int)blockIdx.x - npart1) * TPB + tid;
    if (j < 3 * 2048) {
      int layer = j >> 11;
      int r = j & 2047;
      int kf = r >> 7;
      int nn = r & 127;
      const float* Wl = W + (size_t)layer * 16384;
      half8 v;
#pragma unroll
      for (int jj = 0; jj < 8; jj++) v[jj] = (_Float16)Wl[(kf * 8 + jj) * 128 + nn];
      W16[j] = v;
    }
    return;
  }
  const int bb = blockIdx.x * EPB;
  hist[tid] = 0;
  __syncthreads();
  int sv[8], dv[8];
#pragma unroll
  for (int k = 0; k < 8; k++) {
    int i = bb + tid + k * TPB;
    if (i < E) { sv[k] = src[i]; dv[k] = dst[i]; }
    else { sv[k] = 0; dv[k] = -1; }
  }
#pragma unroll
  for (int k = 0; k < 8; k++)
    if (dv[k] >= 0) atomicAdd(&hist[dv[k] >> 8], 1);
  __syncthreads();
  if (tid < nbins) offs[tid] = hist[tid] ? atomicAdd(&binCnt[tid], hist[tid]) : 0;
  __syncthreads();
#pragma unroll
  for (int k = 0; k < 8; k++) {
    if (dv[k] >= 0) {
      int b = dv[k] >> 8;
      int r = atomicAdd(&offs[b], 1);
      if (r < BCAP)
        binBuf[(size_t)b * BCAP + r] = ((uint)(dv[k] & 255) << 16) | (uint)(ushort)sv[k];
    }
  }
}

// ---------- fused: part2 bucket-build + dis (blocks < nbins) + raw gemm0 t=x@W0 (rest) ----------
__global__ __launch_bounds__(TPB) void part2gemm0_k(const int* __restrict__ binCnt, const uint* __restrict__ binBuf,
                                                    ushort* __restrict__ colidx, int* __restrict__ cnt,
                                                    float* __restrict__ dis,
                                                    const float* __restrict__ x, const half8* __restrict__ W16,
                                                    _Float16* __restrict__ t, int n, int nbins) {
  __shared__ __align__(16) ushort lb[256 * CAP];  // 32 KB
  __shared__ int lc[256];
  const int tid = threadIdx.x;
  if ((int)blockIdx.x < nbins) {
    const int b = blockIdx.x;
    lc[tid] = 0;
    __syncthreads();
    int count = binCnt[b];
    if (count > BCAP) count = BCAP;
    for (int i = tid; i < count; i += TPB) {
      uint p = binBuf[(size_t)b * BCAP + i];
      int dl = (p >> 16) & 255;
      int s = p & 0xFFFF;
      int r = atomicAdd(&lc[dl], 1);
      if (r < CAP) lb[(dl << 6) + r] = (ushort)s;
    }
    __syncthreads();
    uint4* gb = (uint4*)(colidx + (size_t)b * 256 * CAP);
    const uint4* sb = (const uint4*)lb;
#pragma unroll
    for (int k = 0; k < 8; k++) gb[tid + TPB * k] = sb[tid + TPB * k];
    int node = b * 256 + tid;
    if (node < n) {
      cnt[node] = lc[tid];
      dis[node] = rsqrtf((float)(lc[tid] + 1));
    }
    return;
  }
  // gemm0 tile: raw t = x @ W0 (cnt/dis not ready; agg0 applies dis per edge)
  const int g = (int)blockIdx.x - nbins;
  const int lane = tid & 63;
  const int wv = tid >> 6;
  const int m16 = lane & 15;
  const int q = lane >> 4;
  const int r0 = g * 64;
  if (r0 >= n) return;
  half8 bfr[2][4];
#pragma unroll
  for (int nt2 = 0; nt2 < 2; nt2++) {
    const int ncol = 16 * (2 * wv + nt2) + m16;
#pragma unroll
    for (int kit = 0; kit < 4; kit++)
      bfr[nt2][kit] = W16[(kit * 4 + q) * 128 + ncol];
  }
  floatx4 acc[2][4];
#pragma unroll
  for (int a = 0; a < 2; a++)
#pragma unroll
    for (int b2 = 0; b2 < 4; b2++) acc[a][b2] = (floatx4){0.f, 0.f, 0.f, 0.f};
#pragma unroll
  for (int kit = 0; kit < 4; kit++) {
    half8 af[4];
#pragma unroll
    for (int rt = 0; rt < 4; rt++) {
      int row = r0 + 16 * rt + m16;
      half8 a = {0, 0, 0, 0, 0, 0, 0, 0};
      if (row < n) {
        const float4* hp = (const float4*)(x + (size_t)row * 128 + 32 * kit + 8 * q);
        float4 p0 = hp[0], p1 = hp[1];
        a = half8{(_Float16)p0.x, (_Float16)p0.y, (_Float16)p0.z, (_Float16)p0.w,
                  (_Float16)p1.x, (_Float16)p1.y, (_Float16)p1.z, (_Float16)p1.w};
      }
      af[rt] = a;
    }
#pragma unroll
    for (int rt = 0; rt < 4; rt++)
#pragma unroll
      for (int nt2 = 0; nt2 < 2; nt2++)
        acc[nt2][rt] = __builtin_amdgcn_mfma_f32_16x16x32_f16(af[rt], bfr[nt2][kit], acc[nt2][rt], 0, 0, 0);
  }
#pragma unroll
  for (int rt = 0; rt < 4; rt++) {
#pragma unroll
    for (int reg = 0; reg < 4; reg++) {
      int row = r0 + 16 * rt + 4 * q + reg;
      if (row < n) {
#pragma unroll
        for (int nt2 = 0; nt2 < 2; nt2++) {
          int col = 16 * (2 * wv + nt2) + m16;
          t[(size_t)row * 128 + col] = (_Float16)acc[nt2][rt][reg];
        }
      }
    }
  }
}

// ---------- one-row aggregation core: returns post-ELU (cols {2*lane, 2*lane+1}) ----------
#define GATH(k)  int s##k = __builtin_amdgcn_readlane(myIdx, k); uint v##k = t2u[(size_t)s##k * 64 + lane]; \
                 float w##k = SCALE ? dis[s##k] : 1.f;
#define CONS(k)  { float2 f_ = __half22float2(__builtin_bit_cast(__half2, v##k)); \
                   if (SCALE) { a0 = fmaf(f_.x, w##k, a0); a1 = fmaf(f_.y, w##k, a1); } \
                   else { a0 += f_.x; a1 += f_.y; } }

template <bool SCALE>
__device__ __forceinline__ float2 agg_row(int wid, int lane, const uint* __restrict__ t2u,
                                          const int* __restrict__ cnt, const float* __restrict__ dis,
                                          const ushort* __restrict__ colidx, const float* __restrict__ bias) {
  int m = cnt[wid];
  float dd = dis[wid];
  if (m > CAP) m = CAP;
  const size_t base = (size_t)wid * CAP;
  float a0 = 0.f, a1 = 0.f;
  if (m <= 32) {
    int myIdx = wid;  // pad slots -> self row (compensated below)
    if (lane < m) myIdx = (int)colidx[base + lane];
    if (m <= 16) {
      GATH(0) GATH(1) GATH(2) GATH(3) GATH(4) GATH(5) GATH(6) GATH(7)
      GATH(8) GATH(9) GATH(10) GATH(11) GATH(12) GATH(13) GATH(14) GATH(15)
      uint vw = t2u[(size_t)wid * 64 + lane];
      CONS(0) CONS(1) CONS(2) CONS(3) CONS(4) CONS(5) CONS(6) CONS(7)
      CONS(8) CONS(9) CONS(10) CONS(11) CONS(12) CONS(13) CONS(14) CONS(15)
      float2 fw = __half22float2(__builtin_bit_cast(__half2, vw));
      float sc = SCALE ? dd * (float)(m - 15) : (float)(m - 15);
      a0 = fmaf(fw.x, sc, a0); a1 = fmaf(fw.y, sc, a1);
    } else {
      GATH(0) GATH(1) GATH(2) GATH(3) GATH(4) GATH(5) GATH(6) GATH(7)
      GATH(8) GATH(9) GATH(10) GATH(11) GATH(12) GATH(13) GATH(14) GATH(15)
      GATH(16) GATH(17) GATH(18) GATH(19) GATH(20) GATH(21) GATH(22) GATH(23)
      GATH(24) GATH(25) GATH(26) GATH(27) GATH(28) GATH(29) GATH(30) GATH(31)
      uint vw = t2u[(size_t)wid * 64 + lane];
      CONS(0) CONS(1) CONS(2) CONS(3) CONS(4) CONS(5) CONS(6) CONS(7)
      CONS(8) CONS(9) CONS(10) CONS(11) CONS(12) CONS(13) CONS(14) CONS(15)
      CONS(16) CONS(17) CONS(18) CONS(19) CONS(20) CONS(21) CONS(22) CONS(23)
      CONS(24) CONS(25) CONS(26) CONS(27) CONS(28) CONS(29) CONS(30) CONS(31)
      float2 fw = __half22float2(__builtin_bit_cast(__half2, vw));
      float sc = SCALE ? dd * (float)(m - 31) : (float)(m - 31);
      a0 = fmaf(fw.x, sc, a0); a1 = fmaf(fw.y, sc, a1);
    }
  } else {  // 32 < m <= 64, rare
    int myIdx = 0;
    if (lane < m) myIdx = (int)colidx[base + lane];
    for (int e = 0; e < m; e += 8) {
      int s0 = __builtin_amdgcn_readlane(myIdx, e + 0);
      int s1 = __builtin_amdgcn_readlane(myIdx, e + 1);
      int s2 = __builtin_amdgcn_readlane(myIdx, e + 2);
      int s3 = __builtin_amdgcn_readlane(myIdx, e + 3);
      int s4 = __builtin_amdgcn_readlane(myIdx, e + 4);
      int s5 = __builtin_amdgcn_readlane(myIdx, e + 5);
      int s6 = __builtin_amdgcn_readlane(myIdx, e + 6);
      int s7 = __builtin_amdgcn_readlane(myIdx, e + 7);
      uint v0 = t2u[(size_t)s0 * 64 + lane];
      uint v1 = t2u[(size_t)s1 * 64 + lane];
      uint v2 = t2u[(size_t)s2 * 64 + lane];
      uint v3 = t2u[(size_t)s3 * 64 + lane];
      uint v4 = t2u[(size_t)s4 * 64 + lane];
      uint v5 = t2u[(size_t)s5 * 64 + lane];
      uint v6 = t2u[(size_t)s6 * 64 + lane];
      uint v7 = t2u[(size_t)s7 * 64 + lane];
      v1 = (e + 1 < m) ? v1 : 0u;
      v2 = (e + 2 < m) ? v2 : 0u;
      v3 = (e + 3 < m) ? v3 : 0u;
      v4 = (e + 4 < m) ? v4 : 0u;
      v5 = (e + 5 < m) ? v5 : 0u;
      v6 = (e + 6 < m) ? v6 : 0u;
      v7 = (e + 7 < m) ? v7 : 0u;
      float w0 = SCALE ? dis[s0] : 1.f;
      float w1 = SCALE ? dis[s1] : 1.f;
      float w2 = SCALE ? dis[s2] : 1.f;
      float w3 = SCALE ? dis[s3] : 1.f;
      float w4 = SCALE ? dis[s4] : 1.f;
      float w5 = SCALE ? dis[s5] : 1.f;
      float w6 = SCALE ? dis[s6] : 1.f;
      float w7 = SCALE ? dis[s7] : 1.f;
      float2 f;
      f = __half22float2(__builtin_bit_cast(__half2, v0)); a0 = fmaf(f.x, w0, a0); a1 = fmaf(f.y, w0, a1);
      f = __half22float2(__builtin_bit_cast(__half2, v1)); a0 = fmaf(f.x, w1, a0); a1 = fmaf(f.y, w1, a1);
      f = __half22float2(__builtin_bit_cast(__half2, v2)); a0 = fmaf(f.x, w2, a0); a1 = fmaf(f.y, w2, a1);
      f = __half22float2(__builtin_bit_cast(__half2, v3)); a0 = fmaf(f.x, w3, a0); a1 = fmaf(f.y, w3, a1);
      f = __half22float2(__builtin_bit_cast(__half2, v4)); a0 = fmaf(f.x, w4, a0); a1 = fmaf(f.y, w4, a1);
      f = __half22float2(__builtin_bit_cast(__half2, v5)); a0 = fmaf(f.x, w5, a0); a1 = fmaf(f.y, w5, a1);
      f = __half22float2(__builtin_bit_cast(__half2, v6)); a0 = fmaf(f.x, w6, a0); a1 = fmaf(f.y, w6, a1);
      f = __half22float2(__builtin_bit_cast(__half2, v7)); a0 = fmaf(f.x, w7, a0); a1 = fmaf(f.y, w7, a1);
    }
    uint vw = t2u[(size_t)wid * 64 + lane];
    float2 fw = __half22float2(__builtin_bit_cast(__half2, vw));
    float sc = SCALE ? dd : 1.f;
    a0 = fmaf(fw.x, sc, a0); a1 = fmaf(fw.y, sc, a1);
  }
  float2 b = ((const float2*)bias)[lane];
  float r0 = fmaf(a0, dd, b.x);
  float r1 = fmaf(a1, dd, b.y);
  r0 = r0 > 0.f ? r0 : expm1f(r0);
  r1 = r1 > 0.f ? r1 : expm1f(r1);
  return make_float2(r0, r1);
}

// ---------- fused agg_l + gemm_{l+1}: block owns 64 rows; h lives in LDS only ----------
// 512 threads = 8 waves: agg phase 8 rows/wave -> LDS h-tile; gemm phase 1 n-tile/wave.
template <bool SCALE>
__global__ __launch_bounds__(512) void agggemm_k(const uint* __restrict__ t2u, const int* __restrict__ cnt,
                                                 const float* __restrict__ dis,
                                                 const ushort* __restrict__ colidx,
                                                 const float* __restrict__ bias,
                                                 const half8* __restrict__ W16,
                                                 _Float16* __restrict__ tout, int n) {
  __shared__ __align__(16) _Float16 hl[64 * HST];  // 17.4 KB
  const int tid = threadIdx.x;
  const int lane = tid & 63;
  const int wv = tid >> 6;  // 0..7
  const int r0 = blockIdx.x * 64;
  // agg phase: wave wv aggregates local rows 8*wv .. 8*wv+7
#pragma unroll 1
  for (int i = 0; i < 8; i++) {
    int rl = wv * 8 + i;
    int wid = r0 + rl;
    if (wid < n) {
      float2 r = agg_row<SCALE>(wid, lane, t2u, cnt, dis, colidx, bias);
      half2v o = {(_Float16)r.x, (_Float16)r.y};
      *(half2v*)&hl[rl * HST + 2 * lane] = o;
    }
  }
  __syncthreads();
  // gemm phase: wave wv -> n-tile wv (cols 16*wv + m16); A-frags from LDS
  const int m16 = lane & 15;
  const int q = lane >> 4;
  const int ncol = 16 * wv + m16;
  half8 bfr[4];
#pragma unroll
  for (int kit = 0; kit < 4; kit++) bfr[kit] = W16[(kit * 4 + q) * 128 + ncol];
  floatx4 acc[4];
#pragma unroll
  for (int rt = 0; rt < 4; rt++) acc[rt] = (floatx4){0.f, 0.f, 0.f, 0.f};
#pragma unroll
  for (int kit = 0; kit < 4; kit++) {
    half8 af[4];
#pragma unroll
    for (int rt = 0; rt < 4; rt++)
      af[rt] = *(const half8*)&hl[(16 * rt + m16) * HST + 32 * kit + 8 * q];
#pragma unroll
    for (int rt = 0; rt < 4; rt++)
      acc[rt] = __builtin_amdgcn_mfma_f32_16x16x32_f16(af[rt], bfr[kit], acc[rt], 0, 0, 0);
  }
#pragma unroll
  for (int rt = 0; rt < 4; rt++) {
#pragma unroll
    for (int reg = 0; reg < 4; reg++) {
      int row = r0 + 16 * rt + 4 * q + reg;
      if (row < n)
        tout[(size_t)row * 128 + ncol] = (_Float16)(acc[rt][reg] * dis[row]);
    }
  }
}

// ---------- last layer: agg + final projection out = h @ Wl + bl ----------
template <bool SCALE>
__global__ __launch_bounds__(TPB) void aggfinal_k(const uint* __restrict__ t2u, const int* __restrict__ cnt,
                                                  const float* __restrict__ dis,
                                                  const ushort* __restrict__ colidx,
                                                  const float* __restrict__ bias,
                                                  const float* __restrict__ Wl, const float* __restrict__ bl,
                                                  float* __restrict__ out, int n) {
  int wid = (blockIdx.x * TPB + threadIdx.x) >> 6;
  int lane = threadIdx.x & 63;
  if (wid >= n) return;
  float2 r = agg_row<SCALE>(wid, lane, t2u, cnt, dis, colidx, bias);
  float2 wv = ((const float2*)Wl)[lane];
  float s = r.x * wv.x + r.y * wv.y;
  s += __shfl_down(s, 32);
  s += __shfl_down(s, 16);
  s += __shfl_down(s, 8);
  s += __shfl_down(s, 4);
  s += __shfl_down(s, 2);
  s += __shfl_down(s, 1);
  if (lane == 0) out[wid] = s + bl[0];
}

extern "C" void kernel_launch(void* const* d_in, const int* in_sizes, int n_in,
                              void* d_out, int out_size, void* d_ws, size_t ws_size,
                              hipStream_t stream) {
  const int N = in_sizes[0] / 128;
  const int E = in_sizes[5] / 2;
  const int NBINS = (N + 255) >> 8;  // 196
  const float* x  = (const float*)d_in[0];
  const float* Ws = (const float*)d_in[1];
  const float* bs = (const float*)d_in[2];
  const float* Wl = (const float*)d_in[3];
  const float* bl = (const float*)d_in[4];
  const int* ei   = (const int*)d_in[5];
  const int* srcA = ei;
  const int* dstA = ei + E;
  float* out = (float*)d_out;

  char* w = (char*)d_ws;
  size_t o = 0;
  auto alloc = [&](size_t bytes) -> void* {
    void* p = w + o;
    o += (bytes + 255) & ~(size_t)255;
    return p;
  };
  int*       cnt    = (int*)      alloc((size_t)N * 4);
  float*     dis    = (float*)    alloc((size_t)N * 4);
  int*       binCnt = (int*)      alloc((size_t)NBINS * 4);
  uint*      binBuf = (uint*)     alloc((size_t)NBINS * BCAP * 4);
  ushort*    colidx = (ushort*)   alloc((size_t)NBINS * 256 * CAP * 2);
  _Float16*  tbuf   = (_Float16*) alloc((size_t)N * 128 * 2);
  _Float16*  tbuf2  = (_Float16*) alloc((size_t)N * 128 * 2);
  half8*     W16    = (half8*)    alloc((size_t)3 * 2048 * 16);
  (void)ws_size; (void)n_in; (void)out_size;

  const int nbW = (N + 3) / 4;
  const int gemmGrid = (N + 63) / 64;            // 782
  const int npart1 = (E + EPB - 1) / EPB;        // 391
  const int ncvtw = (3 * 2048 + TPB - 1) / TPB;  // 24

  hipMemsetAsync(binCnt, 0, (size_t)NBINS * 4, stream);
  part1cvtw_k<<<npart1 + ncvtw, TPB, 0, stream>>>(srcA, dstA, binCnt, binBuf, Ws, W16,
                                                  E, NBINS, npart1);
  part2gemm0_k<<<NBINS + gemmGrid, TPB, 0, stream>>>(binCnt, binBuf, colidx, cnt, dis,
                                                     x, W16, tbuf, N, NBINS);
  // layer0 agg (raw t -> per-edge dis) + layer1 gemm, h in LDS; t ping-pong
  agggemm_k<true><<<gemmGrid, 512, 0, stream>>>((const uint*)tbuf, cnt, dis, colidx, bs,
                                                W16 + 2048, tbuf2, N);
  // layer1 agg (prescaled t) + layer2 gemm
  agggemm_k<false><<<gemmGrid, 512, 0, stream>>>((const uint*)tbuf2, cnt, dis, colidx, bs + 128,
                                                 W16 + 4096, tbuf, N);
  // layer2 agg + final projection
  aggfinal_k<false><<<nbW, TPB, 0, stream>>>((const uint*)tbuf, cnt, dis, colidx, bs + 256,
                                             Wl, bl, out, N);
}